// Round 2
// baseline (144.480 us; speedup 1.0000x reference)
//
#include <hip/hip_runtime.h>

// ---------------------------------------------------------------------------
// HierarchicalAffinityLoss on MI355X, fp16-MFMA, round 13 (= R12 resubmit;
// R12 bench was an infra failure — container died twice, no counters).
// loss = mean_r relu(maxDot_diff(r) - minDot_same(r) + 0.3), dots of
// row-normalized embeddings. Self-exclusion dropped (self-dot=1.0 never the
// min over ~2000 same-family dots near 0; verified rounds 3-10).
// R12 vs R11 (53.2us gram, 11.8% MfmaUtil, 15.8% occupancy -> latency-bound
// at 8 waves/CU):
//  * 512-thread blocks (8 waves) share one 64-col B tile over a 256-row
//    A-panel: same 2 blocks/CU LDS limit now = 16 waves/CU (4/SIMD), and
//    B staging per MFMA halves. __launch_bounds__(512,4) caps VGPR at 128
//    (129+ drops to 1 block/CU -- cliff).
//  * Family-bias MFMA rank: Eh rows padded to K=288 with 4*onehot(fam) in
//    dims 256..259; A-side fragment scaled by -0.5 -> dot' = dot - 8*[same].
//    min/max over ALL elements then give (minDotSame-8)/maxDotDiff with NO
//    per-element cndmask and NO fam gather/shfls. +8.0f re-bias in f32
//    before fp16 packing keeps stored extremes in [-1,1] (same precision
//    as R11); reduce kernel keeps original thresholds.
//  * Packed (mn,-mx) fp16 reductions via v_pk_min_f16: halves row/col/merge
//    shfl+minmax counts; packed word is already part[]'s format (sign-xor).
//  * Tasks: rb in [0,32) x ct in [4rb,128) = 2112; 528 blocks x exactly 4
//    tasks; C(rb) % 4 == 0 so a block never crosses rb (A loaded once).
//  * Diagonal-task col merges skipped (all-sentinel; also fixes the latent
//    slot(0,0) row-side clobber of R11).
// ---------------------------------------------------------------------------

typedef __attribute__((ext_vector_type(8))) _Float16 half8;  // MFMA A/B frag
typedef __attribute__((ext_vector_type(2))) _Float16 half2v;
typedef __attribute__((ext_vector_type(4))) float floatx4;   // MFMA C/D
typedef __attribute__((ext_vector_type(4))) unsigned short ushort4v;

constexpr int DIN = 256;  // input embedding dim
constexpr int DK  = 288;  // MFMA K: 256 emb + 4 one-hot family + 28 zeros
#define MARGIN 0.3f
// packed family table {0,1,2,1,3,3}, 3 bits each
#define FAM_PACKED 111240
#define SENT 0xC4004400u  // packmm(4.0f, -4.0f): (min,max) neutral pair

// async 16B global -> LDS (wave-uniform LDS base + lane*16)
static __device__ __forceinline__ void ld_g2l16(const unsigned short* g,
                                                unsigned short* l) {
  __builtin_amdgcn_global_load_lds(
      (const __attribute__((address_space(1))) unsigned int*)(const void*)g,
      (__attribute__((address_space(3))) unsigned int*)(void*)l, 16, 0, 0);
}

static __device__ __forceinline__ unsigned packmm(float mn, float mx) {
  unsigned lo = __builtin_bit_cast(unsigned short, (_Float16)mn);
  unsigned hi = __builtin_bit_cast(unsigned short, (_Float16)mx);
  return lo | (hi << 16);
}
static __device__ __forceinline__ float mmlo(unsigned p) {
  return (float)__builtin_bit_cast(_Float16, (unsigned short)(p & 0xFFFF));
}
static __device__ __forceinline__ float mmhi(unsigned p) {
  return (float)__builtin_bit_cast(_Float16, (unsigned short)(p >> 16));
}
// packed elementwise fp16 min -> v_pk_min_f16
static __device__ __forceinline__ unsigned pkmin(unsigned a, unsigned b) {
  half2v x = __builtin_bit_cast(half2v, a);
  half2v y = __builtin_bit_cast(half2v, b);
  return __builtin_bit_cast(unsigned, __builtin_elementwise_min(x, y));
}

// K1: grid-stride waves -> Eh[row][0:256] = fp16(E/||E||),
// Eh[row][256:260] = 4*onehot(fam), Eh[row][260:288] = 0; zero accums.
__global__ __launch_bounds__(256) void prep_kernel(
    const float* __restrict__ E, const int* __restrict__ labels,
    unsigned short* __restrict__ Eh, float* __restrict__ sumAcc,
    int* __restrict__ cntAcc, int* __restrict__ doneCnt, int B) {
  if (blockIdx.x == 0 && threadIdx.x == 0) {
    sumAcc[0] = 0.0f; cntAcc[0] = 0; doneCnt[0] = 0;
  }
  int wave = blockIdx.x * 4 + (threadIdx.x >> 6);
  int lane = threadIdx.x & 63;
  int nw   = gridDim.x * 4;
  for (int row = wave; row < B; row += nw) {
    float4 v = *(const float4*)&E[(long)row * DIN + lane * 4];
    float s = v.x * v.x + v.y * v.y + v.z * v.z + v.w * v.w;
#pragma unroll
    for (int o = 1; o < 64; o <<= 1) s += __shfl_xor(s, o);
    float rn = 1.0f / sqrtf(s);
    ushort4v o4;
    o4.x = __builtin_bit_cast(unsigned short, (_Float16)(v.x * rn));
    o4.y = __builtin_bit_cast(unsigned short, (_Float16)(v.y * rn));
    o4.z = __builtin_bit_cast(unsigned short, (_Float16)(v.z * rn));
    o4.w = __builtin_bit_cast(unsigned short, (_Float16)(v.w * rn));
    *(ushort4v*)&Eh[(long)row * DK + lane * 4] = o4;
    if (lane < 8) {
      ushort4v z = {0, 0, 0, 0};
      if (lane == 0) {
        int lab = labels[row];
        int labc = lab < 0 ? 0 : (lab > 5 ? 5 : lab);
        int fm = (FAM_PACKED >> (3 * labc)) & 7;
        z.x = fm == 0 ? 0x4400 : 0;   // 4.0h
        z.y = fm == 1 ? 0x4400 : 0;
        z.z = fm == 2 ? 0x4400 : 0;
        z.w = fm == 3 ? 0x4400 : 0;
      }
      *(ushort4v*)&Eh[(long)row * DK + DIN + lane * 4] = z;
    }
  }
}

// K2: block = 8 waves, 256-row A-panel (wave w: rows rb*256+w*32, in regs).
// Tasks (rb, ct), ct in [4rb, nt); exactly 4 tasks/block, single rb/block.
// B tile (64 x 288 fp16, 36KB) double-buffered in LDS, XOR-swizzled via
// source permutation. Wave computes its 32x64 tile iff rt64=4rb+(w>>1) <= ct.
// dot' = dot - 8*[same family] via the K=256..287 bias rank. Row-side
// extremes per task -> part[rt64][ct]; col-side partials merged across the
// 8 waves via LDS scratch one task later -> part[ct][rb] (lower triangle).
__global__ __launch_bounds__(512, 4) void gram_kernel(
    const unsigned short* __restrict__ Eh, unsigned* __restrict__ part,
    int nt, int nTasks) {
  __shared__ unsigned short Bs[2][64 * DK];   // 2 x 36 KB
  __shared__ unsigned colS[2][8][64];         // 4 KB scratch

  const int tid = threadIdx.x;
  const int w = tid >> 6, l = tid & 63;
  const int m = l & 15, q = l >> 4;
  const int half = w & 1;
  const int m7 = l & 7;

  // staging: 2304 16B-chunks; rounds 0..3 all 8 waves, round 4 waves 0..3.
  // LDS chunk c holds global (row=c/36, ch<32 ? ch^(row&7) : ch)
  int srcRel[5];
#pragma unroll
  for (int t = 0; t < 5; ++t) {
    int c = (t < 4) ? (t * 512 + w * 64 + l) : (2048 + w * 64 + l);
    int row = c / 36, ch = c - row * 36;
    int sch = (ch < 32) ? (ch ^ (row & 7)) : ch;
    srcRel[t] = row * DK + sch * 8;
  }

  const int t0 = (int)(((long)blockIdx.x * nTasks) / gridDim.x);
  const int t1 = (int)(((long)(blockIdx.x + 1) * nTasks) / gridDim.x);

  // decode t0 -> (rb, ct): C(rb) = rb*(nt - 2*(rb-1)); C(rb+1)=(rb+1)(nt-2rb)
  int rb = 0;
  while ((rb + 1) * (nt - 2 * rb) <= t0) ++rb;
  int ct = 4 * rb + (t0 - rb * (nt - 2 * (rb - 1)));

  const int rt64 = 4 * rb + (w >> 1);

  half8 apan[8][2];
  {
    const int r0w = rb * 256 + w * 32;
#pragma unroll
    for (int ks = 0; ks < 8; ++ks)
#pragma unroll
      for (int mi = 0; mi < 2; ++mi)
        apan[ks][mi] = *(const half8*)
            &Eh[(long)(r0w + mi * 16 + m) * DK + ks * 32 + q * 8];
  }
  // bias-rank A fragment source (loaded per task, transient regs)
  const int aextOff = (rb * 256 + w * 32 + m) * DK + DIN + q * 8;

  // stage first B tile into buffer 0
  {
    const unsigned short* src = Eh + (long)ct * 64 * DK;
#pragma unroll
    for (int t = 0; t < 4; ++t)
      ld_g2l16(src + srcRel[t], &Bs[0][(t * 512 + w * 64) * 8]);
    if (w < 4) ld_g2l16(src + srcRel[4], &Bs[0][(2048 + w * 64) * 8]);
  }

  int p = 0, mct = -1;   // pending col-merge ct (prev task)
#pragma unroll 1
  for (int f = t0; f < t1; ++f) {
    __syncthreads();   // buf[p] staged; prev colS writes visible

    // merge previous task's colS -> part[mct][rb]; skip diagonal task
    // (all-sentinel, and slot would collide with row-side at rb=0)
    if (mct > 4 * rb && l < 8) {
      const int sb2 = (f - 1) & 1;
      const int col = w * 8 + l;
      unsigned a = SENT ^ 0x80000000u;   // (4.0, 4.0) = pk-min neutral
#pragma unroll
      for (int ww = 0; ww < 8; ++ww)
        a = pkmin(a, colS[sb2][ww][col] ^ 0x80000000u);
      part[((long)mct * nt + rb) * 64 + col] = a ^ 0x80000000u;
    }

    const bool doit = (rt64 <= ct);
    const int sb = f & 1;
    floatx4 acc[2][4];
#pragma unroll
    for (int mi = 0; mi < 2; ++mi)
#pragma unroll
      for (int nj = 0; nj < 4; ++nj) acc[mi][nj] = (floatx4)0.0f;

    if (doit) {
      const unsigned short* bufp = &Bs[p][0];
      // family-bias K-block first (aext regs die before the main loop)
      {
        half8 ae[2];
#pragma unroll
        for (int mi = 0; mi < 2; ++mi) {
          ae[mi] = *(const half8*)&Eh[(long)(aextOff + mi * 16 * DK)];
          ae[mi] = ae[mi] * (_Float16)-0.5f;   // 4*onehot -> -2*onehot
        }
        half8 b[4];
#pragma unroll
        for (int nj = 0; nj < 4; ++nj)
          b[nj] = *(const half8*)&bufp[(nj * 16 + m) * DK + (32 + q) * 8];
#pragma unroll
        for (int mi = 0; mi < 2; ++mi)
#pragma unroll
          for (int nj = 0; nj < 4; ++nj)
            acc[mi][nj] = __builtin_amdgcn_mfma_f32_16x16x32_f16(
                ae[mi], b[nj], acc[mi][nj], 0, 0, 0);
      }
#pragma unroll
      for (int ks = 0; ks < 8; ++ks) {
        half8 b[4];
#pragma unroll
        for (int nj = 0; nj < 4; ++nj)
          b[nj] = *(const half8*)
              &bufp[(nj * 16 + m) * DK + (((ks * 4 + q) ^ m7) << 3)];
#pragma unroll
        for (int mi = 0; mi < 2; ++mi)
#pragma unroll
          for (int nj = 0; nj < 4; ++nj)
            acc[mi][nj] = __builtin_amdgcn_mfma_f32_16x16x32_f16(
                apan[ks][mi], b[nj], acc[mi][nj], 0, 0, 0);
      }
    }

    // prefetch next B AFTER this task's ds_reads (no false ordering)
    if (f + 1 < t1) {
      const unsigned short* src = Eh + (long)(ct + 1) * 64 * DK;
#pragma unroll
      for (int t = 0; t < 4; ++t)
        ld_g2l16(src + srcRel[t], &Bs[p ^ 1][(t * 512 + w * 64) * 8]);
      if (w < 4) ld_g2l16(src + srcRel[4], &Bs[p ^ 1][(2048 + w * 64) * 8]);
    }

    if (doit) {
      // ---- epilogue: unmasked min/max of biased dots ----
      float rMn[8], rMx[8];
#pragma unroll
      for (int i = 0; i < 8; ++i) { rMn[i] = 4.0f; rMx[i] = -4.0f; }
      unsigned cPk[4];
#pragma unroll
      for (int nj = 0; nj < 4; ++nj) {
        float cmn = 4.0f, cmx = -4.0f;
#pragma unroll
        for (int mi = 0; mi < 2; ++mi) {
          floatx4 vv = acc[mi][nj];   // C/D: col=l&15, row=q*4+r
#pragma unroll
          for (int r = 0; r < 4; ++r) {
            rMn[mi * 4 + r] = fminf(rMn[mi * 4 + r], vv[r]);
            rMx[mi * 4 + r] = fmaxf(rMx[mi * 4 + r], vv[r]);
          }
          cmn = fminf(cmn, fminf(fminf(vv[0], vv[1]), fminf(vv[2], vv[3])));
          cmx = fmaxf(cmx, fmaxf(fmaxf(vv[0], vv[1]), fmaxf(vv[2], vv[3])));
        }
        // +8 re-bias min (exact in f32); pack (mn,-mx), pk-min over q lanes
        unsigned cp = packmm(cmn + 8.0f, cmx) ^ 0x80000000u;
        cp = pkmin(cp, __shfl_xor(cp, 16));
        cp = pkmin(cp, __shfl_xor(cp, 32));
        cPk[nj] = cp;
      }

      // row side: packed (mn+8, -mx), xor-reduce across the 16 m lanes
      unsigned rp[8];
#pragma unroll
      for (int i = 0; i < 8; ++i)
        rp[i] = packmm(rMn[i] + 8.0f, rMx[i]) ^ 0x80000000u;
#pragma unroll
      for (int o = 1; o < 16; o <<= 1)
#pragma unroll
        for (int i = 0; i < 8; ++i)
          rp[i] = pkmin(rp[i], __shfl_xor(rp[i], o));
      if (m == 0) {
        unsigned* dst = part + ((long)rt64 * nt + ct) * 64;
#pragma unroll
        for (int mi = 0; mi < 2; ++mi)
#pragma unroll
          for (int r = 0; r < 4; ++r)
            dst[half * 32 + mi * 16 + q * 4 + r] =
                rp[mi * 4 + r] ^ 0x80000000u;
      }
      if (q == 0) {
        const bool real = (rt64 < ct);   // diag tile: col side sentinel
#pragma unroll
        for (int nj = 0; nj < 4; ++nj)
          colS[sb][w][nj * 16 + m] = real ? (cPk[nj] ^ 0x80000000u) : SENT;
      }
    } else {
      if (q == 0)
#pragma unroll
        for (int nj = 0; nj < 4; ++nj) colS[sb][w][nj * 16 + m] = SENT;
    }

    mct = ct; ++ct; p ^= 1;
  }

  // tail: merge the last task's colS
  __syncthreads();
  if (mct > 4 * rb && l < 8) {
    const int sb2 = (t1 - 1) & 1;
    const int col = w * 8 + l;
    unsigned a = SENT ^ 0x80000000u;
#pragma unroll
    for (int ww = 0; ww < 8; ++ww)
      a = pkmin(a, colS[sb2][ww][col] ^ 0x80000000u);
    part[((long)mct * nt + rb) * 64 + col] = a ^ 0x80000000u;
  }
}

// K3: 4 threads per row. Row-side: part[rt][k], k in [rt, nt).
// Col-side: part[rt][rb], rb in [0, (rt-1)>>2] (lower-triangle slots), rt>=1.
// Stored mins are re-biased (+8) -> original thresholds/formula apply.
__global__ __launch_bounds__(256) void reduce_kernel(
    const unsigned* __restrict__ part, float* __restrict__ sumAcc,
    int* __restrict__ cntAcc, int* __restrict__ doneCnt,
    float* __restrict__ out, int B, int nt) {
  int gid = blockIdx.x * 256 + threadIdx.x;
  int row = gid >> 2;            // 4 threads per row
  int c   = gid & 3;
  int rt = row >> 6, rl = row & 63;
  const unsigned* base = part + ((long)rt * nt) * 64 + rl;
  float mn = 4.0f, mx = -4.0f;
  for (int k = rt + c; k < nt; k += 4) {
    unsigned pk = base[(long)k * 64];
    mn = fminf(mn, mmlo(pk));
    mx = fmaxf(mx, mmhi(pk));
  }
  if (rt >= 1) {
    int rbmax = (rt - 1) >> 2;   // inclusive; only slots actually written
    for (int k = c; k <= rbmax; k += 4) {
      unsigned pk = base[(long)k * 64];
      mn = fminf(mn, mmlo(pk));
      mx = fmaxf(mx, mmhi(pk));
    }
  }
#pragma unroll
  for (int o = 1; o < 4; o <<= 1) {
    mn = fminf(mn, __shfl_xor(mn, o));
    mx = fmaxf(mx, __shfl_xor(mx, o));
  }
  float loss = 0.0f;
  int cc = 0;
  if (c == 0 && mn < 3.0f && mx > -3.0f) {   // has same && has diff
    loss = fmaxf(mx - mn + MARGIN, 0.0f);
    cc = 1;
  }
#pragma unroll
  for (int o = 1; o < 64; o <<= 1) {
    loss += __shfl_xor(loss, o);
    cc   += __shfl_xor(cc, o);
  }
  __shared__ float ls[4];
  __shared__ int   cs[4];
  if ((threadIdx.x & 63) == 0) {
    ls[threadIdx.x >> 6] = loss;
    cs[threadIdx.x >> 6] = cc;
  }
  __syncthreads();
  if (threadIdx.x == 0) {
    atomicAdd(sumAcc, ls[0] + ls[1] + ls[2] + ls[3]);
    atomicAdd(cntAcc, cs[0] + cs[1] + cs[2] + cs[3]);
    __threadfence();
    int old = atomicAdd(doneCnt, 1);
    if (old == (int)gridDim.x - 1) {
      float S = atomicAdd(sumAcc, 0.0f);   // coherent read
      int   C = atomicAdd(cntAcc, 0);
      out[0] = S / (float)(C > 0 ? C : 1);
    }
  }
}

extern "C" void kernel_launch(void* const* d_in, const int* in_sizes, int n_in,
                              void* d_out, int out_size, void* d_ws, size_t ws_size,
                              hipStream_t stream) {
  const float* E      = (const float*)d_in[0];
  const int*   labels = (const int*)d_in[1];
  float*       out    = (float*)d_out;
  const int B  = in_sizes[1];        // 8192
  const int nt = B / 64;             // 128 col tiles
  const int RB = B / 256;            // 32 row panels of 256 rows
  const int nTasks = RB * (nt - 2 * (RB - 1));   // 32*66 = 2112

  // ws: Eh[B*288] fp16 (4.72MB) | part[nt*nt*64] uint (4MB) | accums
  unsigned short* Eh = (unsigned short*)d_ws;
  unsigned* part     = (unsigned*)(Eh + (size_t)B * DK);
  float* sumAcc      = (float*)(part + (size_t)nt * nt * 64);
  int* cntAcc        = (int*)(sumAcc + 1);
  int* doneCnt       = cntAcc + 1;

  prep_kernel<<<dim3(256), 256, 0, stream>>>(E, labels, Eh,
                                             sumAcc, cntAcc, doneCnt, B);
  // nTasks % 4 == 0 and every C(rb) % 4 == 0 -> 4 tasks/block, single rb
  gram_kernel<<<dim3(nTasks / 4), 512, 0, stream>>>(Eh, part, nt, nTasks);
  reduce_kernel<<<dim3(B * 4 / 256), 256, 0, stream>>>(part, sumAcc, cntAcc,
                                                       doneCnt, out, B, nt);
}

// Round 4
// 137.801 us; speedup vs baseline: 1.0485x; 1.0485x over previous
//
#include <hip/hip_runtime.h>

// ---------------------------------------------------------------------------
// HierarchicalAffinityLoss on MI355X, fp16-MFMA, round 15.
// loss = mean_r relu(maxDot_diff(r) - minDot_same(r) + 0.3), dots of
// row-normalized embeddings. Self-exclusion via bias rank (see below).
// R14 post-mortem: boundary-flush bug — when a block's LAST task closed an
// rb (t1 == C(rb) exactly, e.g. swz=46: t1=254=C(2)), the in-loop flush was
// skipped, rb advanced, and the tail flush wrote old-rb extremes into the
// NEXT rb's rows (absmax 0.75). Fix: flush on every rb-crossing regardless
// of continuation; 'any' reset makes the tail flush a no-op in that case.
// Design (R14, desk-verified): NO LDS, NO barriers.
//  * Eh (4.7MB) is L2/L3-resident (R11 FETCH=16.9MB) -> LDS staging was
//    pure overhead (R11: 7900 cyc/task vs ~900 work, all pipes idle).
//    B fragments loaded per-lane directly from global (L1/L2-cached).
//  * Gram symmetric: col-side extremes fold into the same per-row
//    accumulators as row-side. mnK/mxK[B] hold f32 bits of (biasedExtreme
//    + 10) -- positive floats, so uint atomicMin/Max = float min/max.
//    Col side: 8 fire-and-forget atomics per wave-task. Row side:
//    accumulated in regs across each rb-segment, flushed at crossings.
//  * Bias rank (K=288, dims 256..259 = 4*onehot(fam); A-side scaled -0.5
//    -> dot' = dot - 8*[same]). Self-dot biased to -7, loses to real
//    same-dots (~-8.x) -> self-exclusion free. minSame-8 valid iff < -4;
//    maxDiff valid iff > -4.
//  * Tasks: triangle rb in [0,64) x ct in [2rb,128), 4160 tasks, grid
//    768 x 256, bijective XCD swizzle, 4 independent waves per block.
// ---------------------------------------------------------------------------

typedef __attribute__((ext_vector_type(8))) _Float16 half8;  // MFMA A/B frag
typedef __attribute__((ext_vector_type(4))) float floatx4;   // MFMA C/D
typedef __attribute__((ext_vector_type(4))) unsigned short ushort4v;

constexpr int DIN = 256;  // input embedding dim
constexpr int DK  = 288;  // MFMA K: 256 emb + 4 one-hot family + 28 zeros
#define MARGIN 0.3f
// packed family table {0,1,2,1,3,3}, 3 bits each
#define FAM_PACKED 111240

static __device__ __forceinline__ unsigned fkey(float x) {
  return __builtin_bit_cast(unsigned, x + 10.0f);  // touched values > 0
}

// K1: grid-stride waves -> Eh[row][0:256] = fp16(E/||E||),
// Eh[row][256:260] = 4*onehot(fam), Eh[row][260:288] = 0;
// init mnK = ~0u, mxK = 0u; zero accums.
__global__ __launch_bounds__(256) void prep_kernel(
    const float* __restrict__ E, const int* __restrict__ labels,
    unsigned short* __restrict__ Eh, unsigned* __restrict__ mnK,
    unsigned* __restrict__ mxK, float* __restrict__ sumAcc,
    int* __restrict__ cntAcc, int* __restrict__ doneCnt, int B) {
  if (blockIdx.x == 0 && threadIdx.x == 0) {
    sumAcc[0] = 0.0f; cntAcc[0] = 0; doneCnt[0] = 0;
  }
  int gid = blockIdx.x * 256 + threadIdx.x;
  if (gid < B) { mnK[gid] = 0xFFFFFFFFu; mxK[gid] = 0u; }
  int wave = blockIdx.x * 4 + (threadIdx.x >> 6);
  int lane = threadIdx.x & 63;
  int nw   = gridDim.x * 4;
  for (int row = wave; row < B; row += nw) {
    float4 v = *(const float4*)&E[(long)row * DIN + lane * 4];
    float s = v.x * v.x + v.y * v.y + v.z * v.z + v.w * v.w;
#pragma unroll
    for (int o = 1; o < 64; o <<= 1) s += __shfl_xor(s, o);
    float rn = 1.0f / sqrtf(s);
    ushort4v o4;
    o4.x = __builtin_bit_cast(unsigned short, (_Float16)(v.x * rn));
    o4.y = __builtin_bit_cast(unsigned short, (_Float16)(v.y * rn));
    o4.z = __builtin_bit_cast(unsigned short, (_Float16)(v.z * rn));
    o4.w = __builtin_bit_cast(unsigned short, (_Float16)(v.w * rn));
    *(ushort4v*)&Eh[(long)row * DK + lane * 4] = o4;
    if (lane < 8) {
      ushort4v z = {0, 0, 0, 0};
      if (lane == 0) {
        int lab = labels[row];
        int labc = lab < 0 ? 0 : (lab > 5 ? 5 : lab);
        int fm = (FAM_PACKED >> (3 * labc)) & 7;
        z.x = fm == 0 ? 0x4400 : 0;   // 4.0h
        z.y = fm == 1 ? 0x4400 : 0;
        z.z = fm == 2 ? 0x4400 : 0;
        z.w = fm == 3 ? 0x4400 : 0;
      }
      *(ushort4v*)&Eh[(long)row * DK + DIN + lane * 4] = z;
    }
  }
}

// K2: block = 4 independent waves (no LDS, no barriers). Block owns a
// 128-row A-panel (wave w: rows rb*128+w*32 in regs, incl. bias rank
// pre-scaled by -0.5). Tasks (rb, ct), ct in [2rb, nt); wave computes its
// 32x64 tile vs col tile ct iff rt64 = 2rb+(w>>1) <= ct, loading B frags
// straight from global. Row extremes accumulate in regs across each
// rb-segment (flushed at every crossing); col extremes -> 8 atomics/task.
__global__ __launch_bounds__(256, 2) void gram_kernel(
    const unsigned short* __restrict__ Eh, unsigned* __restrict__ mnK,
    unsigned* __restrict__ mxK, int nt, int nTasks) {
  const int w = threadIdx.x >> 6, l = threadIdx.x & 63;
  const int m = l & 15, q = l >> 4;

  // bijective XCD swizzle (gridDim % 8 == 0)
  const int nwg = gridDim.x;
  const int bid = (int)blockIdx.x;
  const int swz = (bid & 7) * (nwg >> 3) + (bid >> 3);

  const int t0 = (int)(((long)swz * nTasks) / nwg);
  const int t1 = (int)(((long)(swz + 1) * nTasks) / nwg);

  // decode t0 -> (rb, ct): C(rb) = rb*(nt-rb+1); C(rb+1) = (rb+1)*(nt-rb)
  int rb = 0;
  while ((rb + 1) * (nt - rb) <= t0) ++rb;
  int ct = 2 * rb + (t0 - rb * (nt - rb + 1));

  half8 apan[9][2];   // 8 K-blocks of data + bias rank (pre-scaled -0.5)
  auto loadA = [&](int rbv) {
    const int r0w = rbv * 128 + w * 32;
#pragma unroll
    for (int ks = 0; ks < 9; ++ks)
#pragma unroll
      for (int mi = 0; mi < 2; ++mi)
        apan[ks][mi] = *(const half8*)
            &Eh[(long)(r0w + mi * 16 + m) * DK + ks * 32 + q * 8];
    apan[8][0] = apan[8][0] * (_Float16)-0.5f;   // 4*onehot -> -2*onehot
    apan[8][1] = apan[8][1] * (_Float16)-0.5f;
  };
  loadA(rb);

  float rAmn[8], rAmx[8];
  bool any = false;
#pragma unroll
  for (int i = 0; i < 8; ++i) { rAmn[i] = 100.0f; rAmx[i] = -100.0f; }

  auto flushRows = [&](int rbv) {
    if (!any) return;
#pragma unroll
    for (int o = 1; o < 16; o <<= 1)
#pragma unroll
      for (int i = 0; i < 8; ++i) {
        rAmn[i] = fminf(rAmn[i], __shfl_xor(rAmn[i], o));
        rAmx[i] = fmaxf(rAmx[i], __shfl_xor(rAmx[i], o));
      }
    if (m == 0) {
      const int r0 = rbv * 128 + w * 32 + q * 4;
#pragma unroll
      for (int mi = 0; mi < 2; ++mi)
#pragma unroll
        for (int r = 0; r < 4; ++r) {
          int row = r0 + mi * 16 + r;
          atomicMin(&mnK[row], fkey(rAmn[mi * 4 + r]));
          atomicMax(&mxK[row], fkey(rAmx[mi * 4 + r]));
        }
    }
  };

#pragma unroll 1
  for (int f = t0; f < t1; ++f) {
    const int rt64 = 2 * rb + (w >> 1);
    if (rt64 <= ct) {
      any = true;
      const unsigned short* bb = Eh + ((long)(ct * 64 + m)) * DK + q * 8;
      floatx4 acc[2][4];
#pragma unroll
      for (int mi = 0; mi < 2; ++mi)
#pragma unroll
        for (int nj = 0; nj < 4; ++nj) acc[mi][nj] = (floatx4)0.0f;
#pragma unroll
      for (int ks = 0; ks < 9; ++ks) {
        half8 b[4];
#pragma unroll
        for (int nj = 0; nj < 4; ++nj)
          b[nj] = *(const half8*)&bb[nj * 16 * DK + ks * 32];
#pragma unroll
        for (int mi = 0; mi < 2; ++mi)
#pragma unroll
          for (int nj = 0; nj < 4; ++nj)
            acc[mi][nj] = __builtin_amdgcn_mfma_f32_16x16x32_f16(
                apan[ks][mi], b[nj], acc[mi][nj], 0, 0, 0);
      }
      // ---- epilogue: biased extremes; C/D col = nj*16+m, row = mi*16+q*4+r
      float cMn[4], cMx[4];
#pragma unroll
      for (int nj = 0; nj < 4; ++nj) {
        float a0 = fminf(fminf(acc[0][nj][0], acc[0][nj][1]),
                         fminf(acc[0][nj][2], acc[0][nj][3]));
        float a1 = fminf(fminf(acc[1][nj][0], acc[1][nj][1]),
                         fminf(acc[1][nj][2], acc[1][nj][3]));
        float b0 = fmaxf(fmaxf(acc[0][nj][0], acc[0][nj][1]),
                         fmaxf(acc[0][nj][2], acc[0][nj][3]));
        float b1 = fmaxf(fmaxf(acc[1][nj][0], acc[1][nj][1]),
                         fmaxf(acc[1][nj][2], acc[1][nj][3]));
        cMn[nj] = fminf(a0, a1);
        cMx[nj] = fmaxf(b0, b1);
#pragma unroll
        for (int mi = 0; mi < 2; ++mi)
#pragma unroll
          for (int r = 0; r < 4; ++r) {
            rAmn[mi * 4 + r] = fminf(rAmn[mi * 4 + r], acc[mi][nj][r]);
            rAmx[mi * 4 + r] = fmaxf(rAmx[mi * 4 + r], acc[mi][nj][r]);
          }
      }
#pragma unroll
      for (int nj = 0; nj < 4; ++nj) {
        cMn[nj] = fminf(cMn[nj], __shfl_xor(cMn[nj], 16));
        cMn[nj] = fminf(cMn[nj], __shfl_xor(cMn[nj], 32));
        cMx[nj] = fmaxf(cMx[nj], __shfl_xor(cMx[nj], 16));
        cMx[nj] = fmaxf(cMx[nj], __shfl_xor(cMx[nj], 32));
      }
      if (q == 0) {
#pragma unroll
        for (int nj = 0; nj < 4; ++nj) {
          int col = ct * 64 + nj * 16 + m;
          atomicMin(&mnK[col], fkey(cMn[nj]));
          atomicMax(&mxK[col], fkey(cMx[nj]));
        }
      }
    }
    // advance task; FLUSH ON EVERY rb-CROSSING (R14 bug: skipped when the
    // crossing coincided with the block's last task -> wrong-rb tail flush)
    int nct = ct + 1, nrb = rb;
    if (nct == nt) { ++nrb; nct = 2 * nrb; }
    if (nrb != rb) {
      flushRows(rb);
#pragma unroll
      for (int i = 0; i < 8; ++i) { rAmn[i] = 100.0f; rAmx[i] = -100.0f; }
      any = false;
      if (f + 1 < t1) loadA(nrb);
    }
    rb = nrb; ct = nct;
  }
  flushRows(rb);   // no-op (any==false) if last task closed an rb
}

// K3: one thread per row. biasedMin = f(mnK)-10 (= minSame-8 iff a same
// exists, i.e. < -4); biasedMax = f(mxK)-10 (= maxDiff iff > -4).
// loss_r = relu(maxDiff - minSame + 0.3); mean over valid rows.
__global__ __launch_bounds__(256) void reduce_kernel(
    const unsigned* __restrict__ mnK, const unsigned* __restrict__ mxK,
    float* __restrict__ sumAcc, int* __restrict__ cntAcc,
    int* __restrict__ doneCnt, float* __restrict__ out, int B) {
  int gid = blockIdx.x * 256 + threadIdx.x;
  float loss = 0.0f;
  int cc = 0;
  if (gid < B) {
    float bmn = __builtin_bit_cast(float, mnK[gid]) - 10.0f;
    float bmx = __builtin_bit_cast(float, mxK[gid]) - 10.0f;
    if (bmn < -4.0f && bmx > -4.0f) {   // has same && has diff
      loss = fmaxf(bmx - (bmn + 8.0f) + MARGIN, 0.0f);
      cc = 1;
    }
  }
#pragma unroll
  for (int o = 1; o < 64; o <<= 1) {
    loss += __shfl_xor(loss, o);
    cc   += __shfl_xor(cc, o);
  }
  __shared__ float ls[4];
  __shared__ int   cs[4];
  if ((threadIdx.x & 63) == 0) {
    ls[threadIdx.x >> 6] = loss;
    cs[threadIdx.x >> 6] = cc;
  }
  __syncthreads();
  if (threadIdx.x == 0) {
    atomicAdd(sumAcc, ls[0] + ls[1] + ls[2] + ls[3]);
    atomicAdd(cntAcc, cs[0] + cs[1] + cs[2] + cs[3]);
    __threadfence();
    int old = atomicAdd(doneCnt, 1);
    if (old == (int)gridDim.x - 1) {
      float S = atomicAdd(sumAcc, 0.0f);   // coherent read
      int   C = atomicAdd(cntAcc, 0);
      out[0] = S / (float)(C > 0 ? C : 1);
    }
  }
}

extern "C" void kernel_launch(void* const* d_in, const int* in_sizes, int n_in,
                              void* d_out, int out_size, void* d_ws, size_t ws_size,
                              hipStream_t stream) {
  const float* E      = (const float*)d_in[0];
  const int*   labels = (const int*)d_in[1];
  float*       out    = (float*)d_out;
  const int B  = in_sizes[1];        // 8192
  const int nt = B / 64;             // 128 col tiles
  const int RB = B / 128;            // 64 row panels of 128 rows
  const int nTasks = RB * (nt - RB + 1);   // 64*65 = 4160

  // ws: Eh[B*288] fp16 (4.72MB) | mnK[B] | mxK[B] | accums  (~4.79MB)
  unsigned short* Eh = (unsigned short*)d_ws;
  unsigned* mnK      = (unsigned*)(Eh + (size_t)B * DK);
  unsigned* mxK      = mnK + B;
  float* sumAcc      = (float*)(mxK + B);
  int* cntAcc        = (int*)(sumAcc + 1);
  int* doneCnt       = cntAcc + 1;

  prep_kernel<<<dim3(256), 256, 0, stream>>>(E, labels, Eh, mnK, mxK,
                                             sumAcc, cntAcc, doneCnt, B);
  gram_kernel<<<dim3(768), 256, 0, stream>>>(Eh, mnK, mxK, nt, nTasks);
  reduce_kernel<<<dim3((B + 255) / 256), 256, 0, stream>>>(
      mnK, mxK, sumAcc, cntAcc, doneCnt, out, B);
}

// Round 6
// 129.438 us; speedup vs baseline: 1.1162x; 1.0646x over previous
//
#include <hip/hip_runtime.h>

// ---------------------------------------------------------------------------
// HierarchicalAffinityLoss on MI355X, fp16-MFMA, round 17 (= R16 resubmit;
// R16 bench was an infra failure — container died twice, no output. Full
// desk re-audit found no kernel-side hazard; removed one dead duplicate
// store in prep).
// loss = mean_r relu(maxDot_diff(r) - minDot_same(r) + 0.3), dots of
// row-normalized embeddings. Self-exclusion via bias rank.
// R15 post-mortem: correct (absmax 0) but gram 71.4us > R11's 53.2. Cause:
// B-frag loads from row-major Eh scatter 16 lines x 576B apart per wave
// instruction (36/task, ~9.4M line-requests total) with only 2 waves/SIMD
// of cover. HBM 2%, WRITE 11.5MB (= atomics, small) -> VMEM-issue bound.
// R16/R17: ONE change — fragment-linear layout. prep stores
// EhB[tile][ks][nj][lane] = the exact 16B fragment lane l needs: every A/B
// fragment load is a single fully-coalesced 1KB wave-load (16 consecutive
// lines). No layout math in the hot loop. Everything else identical to R15:
//  * NO LDS, NO barriers; 4 independent waves/block; task triangle
//    rb in [0,64) x ct in [2rb,128), 4160 tasks, grid 768, XCD swizzle.
//  * Bias rank (K=288, dims 256..259 = 4*onehot(fam), A-side x-0.5 ->
//    dot' = dot - 8*[same]); self-dot biased to -7 -> self-excl free.
//  * mnK/mxK[B] = f32 bits of (biasedExtreme+10), uint atomicMin/Max;
//    col-side 8 atomics/wave-task, row-side reg-accumulated per
//    rb-segment, flushed at EVERY crossing (R15 fix).
// ---------------------------------------------------------------------------

typedef __attribute__((ext_vector_type(8))) _Float16 half8;  // MFMA A/B frag
typedef __attribute__((ext_vector_type(4))) float floatx4;   // MFMA C/D
typedef __attribute__((ext_vector_type(4))) unsigned short ushort4v;

constexpr int DIN = 256;  // input embedding dim
constexpr int NKS = 9;    // K blocks of 32: 8 data + 1 bias
// fragment-linear tile: [ks 0..8][nj 0..3][lane 0..63][8 halves]
constexpr int TILE_USH = NKS * 4 * 64 * 8;   // 18432 ushorts = 36KB per tile
#define MARGIN 0.3f
// packed family table {0,1,2,1,3,3}, 3 bits each
#define FAM_PACKED 111240

static __device__ __forceinline__ unsigned fkey(float x) {
  return __builtin_bit_cast(unsigned, x + 10.0f);  // touched values > 0
}

// K1: grid-stride waves; row r -> tile ct=r>>6, nj=(r>>4)&3, mrow=r&15.
// Lane holds elems e=lane*4..+3: ks=lane>>3, q=(lane>>1)&3, o=(lane&1)*4.
// EhB[((ct*9+ks)*4+nj)*512 + (q*16+mrow)*8 + o] = fp16(E/||E||) (e<256);
// ks=8 block: 4*onehot(fam) at e=256..259, zeros elsewhere.
__global__ __launch_bounds__(256) void prep_kernel(
    const float* __restrict__ E, const int* __restrict__ labels,
    unsigned short* __restrict__ EhB, unsigned* __restrict__ mnK,
    unsigned* __restrict__ mxK, float* __restrict__ sumAcc,
    int* __restrict__ cntAcc, int* __restrict__ doneCnt, int B) {
  if (blockIdx.x == 0 && threadIdx.x == 0) {
    sumAcc[0] = 0.0f; cntAcc[0] = 0; doneCnt[0] = 0;
  }
  int gid = blockIdx.x * 256 + threadIdx.x;
  if (gid < B) { mnK[gid] = 0xFFFFFFFFu; mxK[gid] = 0u; }
  int wave = blockIdx.x * 4 + (threadIdx.x >> 6);
  int lane = threadIdx.x & 63;
  int nw   = gridDim.x * 4;
  const int ksl = lane >> 3, ql = (lane >> 1) & 3, ol = (lane & 1) * 4;
  for (int row = wave; row < B; row += nw) {
    float4 v = *(const float4*)&E[(long)row * DIN + lane * 4];
    float s = v.x * v.x + v.y * v.y + v.z * v.z + v.w * v.w;
#pragma unroll
    for (int o = 1; o < 64; o <<= 1) s += __shfl_xor(s, o);
    float rn = 1.0f / sqrtf(s);
    ushort4v o4;
    o4.x = __builtin_bit_cast(unsigned short, (_Float16)(v.x * rn));
    o4.y = __builtin_bit_cast(unsigned short, (_Float16)(v.y * rn));
    o4.z = __builtin_bit_cast(unsigned short, (_Float16)(v.z * rn));
    o4.w = __builtin_bit_cast(unsigned short, (_Float16)(v.w * rn));
    const int ct = row >> 6, nj = (row >> 4) & 3, mrow = row & 15;
    const long tbase = (long)ct * TILE_USH;
    *(ushort4v*)&EhB[tbase + ((long)(ksl * 4 + nj) * 64 + ql * 16 + mrow) * 8
                     + ol] = o4;
    if (lane < 8) {   // bias block ks=8: elems 256..287
      ushort4v z = {0, 0, 0, 0};
      if (lane == 0) {
        int lab = labels[row];
        int labc = lab < 0 ? 0 : (lab > 5 ? 5 : lab);
        int fm = (FAM_PACKED >> (3 * labc)) & 7;
        z.x = fm == 0 ? 0x4400 : 0;   // 4.0h
        z.y = fm == 1 ? 0x4400 : 0;
        z.z = fm == 2 ? 0x4400 : 0;
        z.w = fm == 3 ? 0x4400 : 0;
      }
      *(ushort4v*)&EhB[tbase + ((long)(8 * 4 + nj) * 64 + ql * 16 + mrow) * 8
                       + ol] = z;
    }
  }
}

// K2: block = 4 independent waves (no LDS, no barriers). Wave w owns rows
// rb*128+w*32 (A tile 2rb+(w>>1), nj' = (w&1)*2+mi) resident in regs.
// Tasks (rb, ct), ct in [2rb, nt); wave computes its 32x64 tile iff
// rt64 <= ct. All fragment loads are coalesced 1KB wave-loads from EhB.
__global__ __launch_bounds__(256, 2) void gram_kernel(
    const unsigned short* __restrict__ EhB, unsigned* __restrict__ mnK,
    unsigned* __restrict__ mxK, int nt, int nTasks) {
  const int w = threadIdx.x >> 6, l = threadIdx.x & 63;
  const int m = l & 15, q = l >> 4;

  // bijective XCD swizzle (gridDim % 8 == 0)
  const int nwg = gridDim.x;
  const int bid = (int)blockIdx.x;
  const int swz = (bid & 7) * (nwg >> 3) + (bid >> 3);

  const int t0 = (int)(((long)swz * nTasks) / nwg);
  const int t1 = (int)(((long)(swz + 1) * nTasks) / nwg);

  // decode t0 -> (rb, ct): C(rb) = rb*(nt-rb+1); C(rb+1) = (rb+1)*(nt-rb)
  int rb = 0;
  while ((rb + 1) * (nt - rb) <= t0) ++rb;
  int ct = 2 * rb + (t0 - rb * (nt - rb + 1));

  const unsigned short* baseL = EhB + l * 8;   // lane's fragment column

  half8 apan[NKS][2];   // 8 data K-blocks + bias (pre-scaled -0.5)
  auto loadA = [&](int rbv) {
    const long at = (long)(2 * rbv + (w >> 1)) * TILE_USH;
#pragma unroll
    for (int ks = 0; ks < NKS; ++ks)
#pragma unroll
      for (int mi = 0; mi < 2; ++mi)
        apan[ks][mi] = *(const half8*)
            &baseL[at + (long)(ks * 4 + (w & 1) * 2 + mi) * 512];
    apan[8][0] = apan[8][0] * (_Float16)-0.5f;   // 4*onehot -> -2*onehot
    apan[8][1] = apan[8][1] * (_Float16)-0.5f;
  };
  loadA(rb);

  float rAmn[8], rAmx[8];
  bool any = false;
#pragma unroll
  for (int i = 0; i < 8; ++i) { rAmn[i] = 100.0f; rAmx[i] = -100.0f; }

  auto flushRows = [&](int rbv) {
    if (!any) return;
#pragma unroll
    for (int o = 1; o < 16; o <<= 1)
#pragma unroll
      for (int i = 0; i < 8; ++i) {
        rAmn[i] = fminf(rAmn[i], __shfl_xor(rAmn[i], o));
        rAmx[i] = fmaxf(rAmx[i], __shfl_xor(rAmx[i], o));
      }
    if (m == 0) {
      const int r0 = rbv * 128 + w * 32 + q * 4;
#pragma unroll
      for (int mi = 0; mi < 2; ++mi)
#pragma unroll
        for (int r = 0; r < 4; ++r) {
          int row = r0 + mi * 16 + r;
          atomicMin(&mnK[row], fkey(rAmn[mi * 4 + r]));
          atomicMax(&mxK[row], fkey(rAmx[mi * 4 + r]));
        }
    }
  };

#pragma unroll 1
  for (int f = t0; f < t1; ++f) {
    const int rt64 = 2 * rb + (w >> 1);
    if (rt64 <= ct) {
      any = true;
      const unsigned short* bt = baseL + (long)ct * TILE_USH;
      floatx4 acc[2][4];
#pragma unroll
      for (int mi = 0; mi < 2; ++mi)
#pragma unroll
        for (int nj = 0; nj < 4; ++nj) acc[mi][nj] = (floatx4)0.0f;
#pragma unroll
      for (int ks = 0; ks < NKS; ++ks) {
        half8 b[4];
#pragma unroll
        for (int nj = 0; nj < 4; ++nj)
          b[nj] = *(const half8*)&bt[(long)(ks * 4 + nj) * 512];
#pragma unroll
        for (int mi = 0; mi < 2; ++mi)
#pragma unroll
          for (int nj = 0; nj < 4; ++nj)
            acc[mi][nj] = __builtin_amdgcn_mfma_f32_16x16x32_f16(
                apan[ks][mi], b[nj], acc[mi][nj], 0, 0, 0);
      }
      // ---- epilogue: biased extremes; C/D col = nj*16+m, row = mi*16+q*4+r
      float cMn[4], cMx[4];
#pragma unroll
      for (int nj = 0; nj < 4; ++nj) {
        float a0 = fminf(fminf(acc[0][nj][0], acc[0][nj][1]),
                         fminf(acc[0][nj][2], acc[0][nj][3]));
        float a1 = fminf(fminf(acc[1][nj][0], acc[1][nj][1]),
                         fminf(acc[1][nj][2], acc[1][nj][3]));
        float b0 = fmaxf(fmaxf(acc[0][nj][0], acc[0][nj][1]),
                         fmaxf(acc[0][nj][2], acc[0][nj][3]));
        float b1 = fmaxf(fmaxf(acc[1][nj][0], acc[1][nj][1]),
                         fmaxf(acc[1][nj][2], acc[1][nj][3]));
        cMn[nj] = fminf(a0, a1);
        cMx[nj] = fmaxf(b0, b1);
#pragma unroll
        for (int mi = 0; mi < 2; ++mi)
#pragma unroll
          for (int r = 0; r < 4; ++r) {
            rAmn[mi * 4 + r] = fminf(rAmn[mi * 4 + r], acc[mi][nj][r]);
            rAmx[mi * 4 + r] = fmaxf(rAmx[mi * 4 + r], acc[mi][nj][r]);
          }
      }
#pragma unroll
      for (int nj = 0; nj < 4; ++nj) {
        cMn[nj] = fminf(cMn[nj], __shfl_xor(cMn[nj], 16));
        cMn[nj] = fminf(cMn[nj], __shfl_xor(cMn[nj], 32));
        cMx[nj] = fmaxf(cMx[nj], __shfl_xor(cMx[nj], 16));
        cMx[nj] = fmaxf(cMx[nj], __shfl_xor(cMx[nj], 32));
      }
      if (q == 0) {
#pragma unroll
        for (int nj = 0; nj < 4; ++nj) {
          int col = ct * 64 + nj * 16 + m;
          atomicMin(&mnK[col], fkey(cMn[nj]));
          atomicMax(&mxK[col], fkey(cMx[nj]));
        }
      }
    }
    // advance; flush on EVERY rb-crossing (R15 fix)
    int nct = ct + 1, nrb = rb;
    if (nct == nt) { ++nrb; nct = 2 * nrb; }
    if (nrb != rb) {
      flushRows(rb);
#pragma unroll
      for (int i = 0; i < 8; ++i) { rAmn[i] = 100.0f; rAmx[i] = -100.0f; }
      any = false;
      if (f + 1 < t1) loadA(nrb);
    }
    rb = nrb; ct = nct;
  }
  flushRows(rb);   // no-op (any==false) if last task closed an rb
}

// K3: one thread per row. biasedMin = f(mnK)-10 (= minSame-8 iff < -4);
// biasedMax = f(mxK)-10 (= maxDiff iff > -4).
__global__ __launch_bounds__(256) void reduce_kernel(
    const unsigned* __restrict__ mnK, const unsigned* __restrict__ mxK,
    float* __restrict__ sumAcc, int* __restrict__ cntAcc,
    int* __restrict__ doneCnt, float* __restrict__ out, int B) {
  int gid = blockIdx.x * 256 + threadIdx.x;
  float loss = 0.0f;
  int cc = 0;
  if (gid < B) {
    float bmn = __builtin_bit_cast(float, mnK[gid]) - 10.0f;
    float bmx = __builtin_bit_cast(float, mxK[gid]) - 10.0f;
    if (bmn < -4.0f && bmx > -4.0f) {   // has same && has diff
      loss = fmaxf(bmx - (bmn + 8.0f) + MARGIN, 0.0f);
      cc = 1;
    }
  }
#pragma unroll
  for (int o = 1; o < 64; o <<= 1) {
    loss += __shfl_xor(loss, o);
    cc   += __shfl_xor(cc, o);
  }
  __shared__ float ls[4];
  __shared__ int   cs[4];
  if ((threadIdx.x & 63) == 0) {
    ls[threadIdx.x >> 6] = loss;
    cs[threadIdx.x >> 6] = cc;
  }
  __syncthreads();
  if (threadIdx.x == 0) {
    atomicAdd(sumAcc, ls[0] + ls[1] + ls[2] + ls[3]);
    atomicAdd(cntAcc, cs[0] + cs[1] + cs[2] + cs[3]);
    __threadfence();
    int old = atomicAdd(doneCnt, 1);
    if (old == (int)gridDim.x - 1) {
      float S = atomicAdd(sumAcc, 0.0f);   // coherent read
      int   C = atomicAdd(cntAcc, 0);
      out[0] = S / (float)(C > 0 ? C : 1);
    }
  }
}

extern "C" void kernel_launch(void* const* d_in, const int* in_sizes, int n_in,
                              void* d_out, int out_size, void* d_ws, size_t ws_size,
                              hipStream_t stream) {
  const float* E      = (const float*)d_in[0];
  const int*   labels = (const int*)d_in[1];
  float*       out    = (float*)d_out;
  const int B  = in_sizes[1];        // 8192
  const int nt = B / 64;             // 128 col tiles
  const int RB = B / 128;            // 64 row panels of 128 rows
  const int nTasks = RB * (nt - RB + 1);   // 64*65 = 4160

  // ws: EhB[nt*36KB] (4.72MB) | mnK[B] | mxK[B] | accums  (~4.79MB)
  unsigned short* EhB = (unsigned short*)d_ws;
  unsigned* mnK       = (unsigned*)(EhB + (size_t)nt * TILE_USH);
  unsigned* mxK       = mnK + B;
  float* sumAcc       = (float*)(mxK + B);
  int* cntAcc         = (int*)(sumAcc + 1);
  int* doneCnt        = cntAcc + 1;

  prep_kernel<<<dim3(256), 256, 0, stream>>>(E, labels, EhB, mnK, mxK,
                                             sumAcc, cntAcc, doneCnt, B);
  gram_kernel<<<dim3(768), 256, 0, stream>>>(EhB, mnK, mxK, nt, nTasks);
  reduce_kernel<<<dim3((B + 255) / 256), 256, 0, stream>>>(
      mnK, mxK, sumAcc, cntAcc, doneCnt, out, B);
}